// Round 1
// baseline (251.600 us; speedup 1.0000x reference)
//
#include <hip/hip_runtime.h>
#include <hip/hip_bf16.h>

#define NN 4096

typedef __attribute__((ext_vector_type(8))) short short8;
typedef __attribute__((ext_vector_type(4))) float f32x4;

// fp32 -> bf16 round-to-nearest-even (inputs are finite randoms; no NaN care)
static __device__ __forceinline__ unsigned short f2bf(float x) {
    unsigned int u = __float_as_uint(x);
    u += 0x7fffu + ((u >> 16) & 1u);
    return (unsigned short)(u >> 16);
}

// async global->LDS, 16 bytes per lane (dest = wave-uniform base + lane*16)
static __device__ __forceinline__ void load_lds16(const unsigned short* g, unsigned short* l) {
    __builtin_amdgcn_global_load_lds(
        (const __attribute__((address_space(1))) unsigned int*)g,
        (__attribute__((address_space(3))) unsigned int*)l,
        16, 0, 0);
}

// ---------------- pre-pass 1: A -> bf16, masked tril (keep k <= i) ----------------
__global__ __launch_bounds__(256) void convA(const float* __restrict__ A,
                                             unsigned short* __restrict__ Abf) {
    int t = blockIdx.x * 256 + threadIdx.x;     // float4 index, total 4096*1024
    int row = t >> 10;                          // 1024 float4 per row
    int c4 = (t & 1023) << 2;
    const float4 v = *(const float4*)(A + ((size_t)row << 12) + c4);
    ushort4 o;
    o.x = (c4 + 0 <= row) ? f2bf(v.x) : (unsigned short)0;
    o.y = (c4 + 1 <= row) ? f2bf(v.y) : (unsigned short)0;
    o.z = (c4 + 2 <= row) ? f2bf(v.z) : (unsigned short)0;
    o.w = (c4 + 3 <= row) ? f2bf(v.w) : (unsigned short)0;
    *(ushort4*)(Abf + ((size_t)row << 12) + c4) = o;
}

// ------------- pre-pass 2: B -> bf16, masked tril (keep k >= j), transposed -------------
// Bt[n][k] = (k >= n) ? bf16(B[k][n]) : 0
__global__ __launch_bounds__(256) void convB(const float* __restrict__ B,
                                             unsigned short* __restrict__ Bt) {
    __shared__ float tile[64][65];
    const int n0 = blockIdx.x * 64;
    const int k0 = blockIdx.y * 64;
    const int t = threadIdx.x;
    #pragma unroll
    for (int p = 0; p < 4; ++p) {
        int idx = p * 256 + t;                  // float4 id in 64x64 tile
        int kr  = idx >> 4;                     // 16 float4 per k-row
        int c4  = (idx & 15) << 2;
        const float4 v = *(const float4*)(B + (size_t)(k0 + kr) * NN + n0 + c4);
        tile[kr][c4 + 0] = v.x; tile[kr][c4 + 1] = v.y;
        tile[kr][c4 + 2] = v.z; tile[kr][c4 + 3] = v.w;
    }
    __syncthreads();
    #pragma unroll
    for (int p = 0; p < 4; ++p) {
        int idx = p * 256 + t;
        int nr  = idx >> 4;                     // output n-row
        int k4  = (idx & 15) << 2;
        int gn  = n0 + nr;
        ushort4 o;
        o.x = (k0 + k4 + 0 >= gn) ? f2bf(tile[k4 + 0][nr]) : (unsigned short)0;
        o.y = (k0 + k4 + 1 >= gn) ? f2bf(tile[k4 + 1][nr]) : (unsigned short)0;
        o.z = (k0 + k4 + 2 >= gn) ? f2bf(tile[k4 + 2][nr]) : (unsigned short)0;
        o.w = (k0 + k4 + 3 >= gn) ? f2bf(tile[k4 + 3][nr]) : (unsigned short)0;
        *(ushort4*)(Bt + (size_t)gn * NN + k0 + k4) = o;
    }
}

// ---------------- main GEMM: 128x128 tile, BK=32, m97-style ----------------
// grid.x = 1024: [0,528) = lower-tri compute blocks (longest-first), [528,1024) = zero-fill upper
__global__ __launch_bounds__(256, 2) void gemm_tril(const unsigned short* __restrict__ Abf,
                                                    const unsigned short* __restrict__ Btb,
                                                    float* __restrict__ C) {
    const int t = blockIdx.x;
    const int tid = threadIdx.x;

    if (t >= 528) {
        // strict-upper 128x128 block: write zeros (d_out is poisoned)
        int u = t - 528;
        int e = (int)((sqrtf(8.f * (float)u + 1.f) - 1.f) * 0.5f);
        while ((e + 1) * (e + 2) / 2 <= u) ++e;
        while (e * (e + 1) / 2 > u) --e;
        int r = u - e * (e + 1) / 2;
        int bi = r, bj = e + 1;                 // bi < bj
        float4 z = make_float4(0.f, 0.f, 0.f, 0.f);
        #pragma unroll
        for (int it = 0; it < 16; ++it) {
            int idx = it * 256 + tid;           // float4 id in 128x128 tile
            int rr = idx >> 5;                  // 32 float4 per row
            int c4 = (idx & 31) << 2;
            *(float4*)&C[(size_t)(bi * 128 + rr) * NN + bj * 128 + c4] = z;
        }
        return;
    }

    // decode lower-tri pair, longest diagonal-distance first
    int e = (int)((sqrtf(8.f * (float)t + 1.f) - 1.f) * 0.5f);
    while ((e + 1) * (e + 2) / 2 <= t) ++e;
    while (e * (e + 1) / 2 > t) --e;
    int r = t - e * (e + 1) / 2;
    const int bj = r;
    const int bi = r + 31 - e;                  // bi >= bj

    __shared__ __attribute__((aligned(16))) unsigned short As[128 * 32];
    __shared__ __attribute__((aligned(16))) unsigned short Bs[128 * 32];

    const int lane = tid & 63;
    const int w    = tid >> 6;
    const int wm   = w >> 1, wn = w & 1;
    const int l15  = lane & 15, quad = lane >> 4;

    f32x4 acc[4][4];
    const f32x4 zero4 = {0.f, 0.f, 0.f, 0.f};
    #pragma unroll
    for (int i = 0; i < 4; ++i)
        #pragma unroll
        for (int j = 0; j < 4; ++j) acc[i][j] = zero4;

    const int kb0 = bj << 2, kb1 = (bi << 2) + 3;   // BK=32 blocks, k in [128*bj, 128*bi+127]

    for (int kb = kb0; kb <= kb1; ++kb) {
        const int koff = kb << 5;
        #pragma unroll
        for (int u2 = 0; u2 < 2; ++u2) {
            int ci   = u2 * 256 + tid;          // 16B chunk id, 512 per tile
            int rowA = ci >> 2;                 // 4 chunks (64B) per row
            int q    = ci & 3;
            load_lds16(Abf + (size_t)(bi * 128 + rowA) * NN + koff + q * 8, &As[ci * 8]);
            load_lds16(Btb + (size_t)(bj * 128 + rowA) * NN + koff + q * 8, &Bs[ci * 8]);
        }
        __syncthreads();                        // drains vmcnt (global_load_lds) too

        short8 a[4], b[4];
        #pragma unroll
        for (int mt = 0; mt < 4; ++mt)
            a[mt] = *(const short8*)&As[(wm * 64 + mt * 16 + l15) * 32 + quad * 8];
        #pragma unroll
        for (int nt = 0; nt < 4; ++nt)
            b[nt] = *(const short8*)&Bs[(wn * 64 + nt * 16 + l15) * 32 + quad * 8];
        #pragma unroll
        for (int mt = 0; mt < 4; ++mt)
            #pragma unroll
            for (int nt = 0; nt < 4; ++nt)
                acc[mt][nt] = __builtin_amdgcn_mfma_f32_16x16x32_bf16(a[mt], b[nt], acc[mt][nt], 0, 0, 0);
        __syncthreads();
    }

    // epilogue: C/D layout col=lane&15, row=quad*4+reg (m89-verified); mask i>=j
    #pragma unroll
    for (int mt = 0; mt < 4; ++mt) {
        #pragma unroll
        for (int nt = 0; nt < 4; ++nt) {
            const int gj  = bj * 128 + wn * 64 + nt * 16 + l15;
            const int gi0 = bi * 128 + wm * 64 + mt * 16 + quad * 4;
            #pragma unroll
            for (int rr = 0; rr < 4; ++rr) {
                int gi = gi0 + rr;
                float v = acc[mt][nt][rr];
                C[(size_t)gi * NN + gj] = (gi >= gj) ? v : 0.f;
            }
        }
    }
}

// ---------------- fallback (ws too small): fp32 LDS-tiled, correct-but-slow ----------------
__global__ void gemm_fallback(const float* __restrict__ A, const float* __restrict__ B,
                              float* __restrict__ C) {
    const int bi = blockIdx.y, bj = blockIdx.x;     // 32x32 tiles
    const int ty = threadIdx.y, tx = threadIdx.x;
    const int gi = bi * 32 + ty, gj = bj * 32 + tx;
    if (bi < bj) { C[(size_t)gi * NN + gj] = 0.f; return; }
    __shared__ float As[32][33], Bs[32][33];
    float s = 0.f;
    for (int kt = bj; kt <= bi; ++kt) {
        const int k = kt * 32;
        float av = A[(size_t)gi * NN + k + tx];
        As[ty][tx] = (k + tx <= gi) ? av : 0.f;
        float bv = B[(size_t)(k + ty) * NN + gj];
        Bs[ty][tx] = (k + ty >= gj) ? bv : 0.f;
        __syncthreads();
        #pragma unroll
        for (int kk = 0; kk < 32; ++kk) s += As[ty][kk] * Bs[kk][tx];
        __syncthreads();
    }
    C[(size_t)gi * NN + gj] = (gi >= gj) ? s : 0.f;
}

extern "C" void kernel_launch(void* const* d_in, const int* in_sizes, int n_in,
                              void* d_out, int out_size, void* d_ws, size_t ws_size,
                              hipStream_t stream) {
    const float* A = (const float*)d_in[0];
    const float* B = (const float*)d_in[1];
    float* C = (float*)d_out;

    const size_t need = (size_t)2 * NN * NN * sizeof(unsigned short);  // 64 MB
    if (ws_size >= need) {
        unsigned short* Abf = (unsigned short*)d_ws;
        unsigned short* Btb = Abf + (size_t)NN * NN;
        convA<<<dim3(16384), dim3(256), 0, stream>>>(A, Abf);
        convB<<<dim3(64, 64), dim3(256), 0, stream>>>(B, Btb);
        gemm_tril<<<dim3(1024), dim3(256), 0, stream>>>(Abf, Btb, C);
    } else {
        gemm_fallback<<<dim3(128, 128), dim3(32, 32), 0, stream>>>(A, B, C);
    }
}

// Round 2
// 249.248 us; speedup vs baseline: 1.0094x; 1.0094x over previous
//
#include <hip/hip_runtime.h>
#include <hip/hip_bf16.h>

#define NN 4096

typedef __attribute__((ext_vector_type(8))) short short8;
typedef __attribute__((ext_vector_type(4))) float f32x4;

// fp32 -> bf16 round-to-nearest-even
static __device__ __forceinline__ unsigned short f2bf(float x) {
    unsigned int u = __float_as_uint(x);
    u += 0x7fffu + ((u >> 16) & 1u);
    return (unsigned short)(u >> 16);
}

// async global->LDS, 16 bytes per lane (dest = wave-uniform base + lane*16)
static __device__ __forceinline__ void load_lds16(const unsigned short* g, unsigned short* l) {
    __builtin_amdgcn_global_load_lds(
        (const __attribute__((address_space(1))) unsigned int*)g,
        (__attribute__((address_space(3))) unsigned int*)l,
        16, 0, 0);
}

// ---------------- pre-pass 1: A -> bf16, masked tril (keep k <= i) ----------------
__global__ __launch_bounds__(256) void convA(const float* __restrict__ A,
                                             unsigned short* __restrict__ Abf) {
    int t = blockIdx.x * 256 + threadIdx.x;     // float4 index, total 4096*1024
    int row = t >> 10;
    int c4 = (t & 1023) << 2;
    const float4 v = *(const float4*)(A + ((size_t)row << 12) + c4);
    ushort4 o;
    o.x = (c4 + 0 <= row) ? f2bf(v.x) : (unsigned short)0;
    o.y = (c4 + 1 <= row) ? f2bf(v.y) : (unsigned short)0;
    o.z = (c4 + 2 <= row) ? f2bf(v.z) : (unsigned short)0;
    o.w = (c4 + 3 <= row) ? f2bf(v.w) : (unsigned short)0;
    *(ushort4*)(Abf + ((size_t)row << 12) + c4) = o;
}

// ------------- pre-pass 2: B -> bf16, masked tril (keep k >= j), transposed -------------
// Bt[n][k] = (k >= n) ? bf16(B[k][n]) : 0
__global__ __launch_bounds__(256) void convB(const float* __restrict__ B,
                                             unsigned short* __restrict__ Bt) {
    __shared__ float tile[64][65];
    const int n0 = blockIdx.x * 64;
    const int k0 = blockIdx.y * 64;
    const int t = threadIdx.x;
    #pragma unroll
    for (int p = 0; p < 4; ++p) {
        int idx = p * 256 + t;                  // float4 id in 64x64 tile
        int kr  = idx >> 4;
        int c4  = (idx & 15) << 2;
        const float4 v = *(const float4*)(B + (size_t)(k0 + kr) * NN + n0 + c4);
        tile[kr][c4 + 0] = v.x; tile[kr][c4 + 1] = v.y;
        tile[kr][c4 + 2] = v.z; tile[kr][c4 + 3] = v.w;
    }
    __syncthreads();
    #pragma unroll
    for (int p = 0; p < 4; ++p) {
        int idx = p * 256 + t;
        int nr  = idx >> 4;
        int k4  = (idx & 15) << 2;
        int gn  = n0 + nr;
        ushort4 o;
        o.x = (k0 + k4 + 0 >= gn) ? f2bf(tile[k4 + 0][nr]) : (unsigned short)0;
        o.y = (k0 + k4 + 1 >= gn) ? f2bf(tile[k4 + 1][nr]) : (unsigned short)0;
        o.z = (k0 + k4 + 2 >= gn) ? f2bf(tile[k4 + 2][nr]) : (unsigned short)0;
        o.w = (k0 + k4 + 3 >= gn) ? f2bf(tile[k4 + 3][nr]) : (unsigned short)0;
        *(ushort4*)(Bt + (size_t)gn * NN + k0 + k4) = o;
    }
}

// ---------------- prep: zero strict-upper tiles (496) + multi-chunk lower tiles (300) ----------------
__global__ __launch_bounds__(256) void prep_zero(float* __restrict__ C) {
    const int t = blockIdx.x;
    const int tid = threadIdx.x;
    int bi, bj;
    if (t < 496) {
        // strict-upper: bi < bj
        int u = t;
        int e = (int)((sqrtf(8.f * (float)u + 1.f) - 1.f) * 0.5f);
        while ((e + 1) * (e + 2) / 2 <= u) ++e;
        while (e * (e + 1) / 2 > u) --e;
        int r = u - e * (e + 1) / 2;
        bi = r; bj = e + 1;
    } else {
        // lower tiles with d = bi-bj >= 8 (these get atomicAdd partials)
        int u = t - 496;
        int d = 8;
        for (; d < 32; ++d) { int cnt = 32 - d; if (u < cnt) break; u -= cnt; }
        bj = u; bi = u + d;
    }
    const float4 z = make_float4(0.f, 0.f, 0.f, 0.f);
    #pragma unroll
    for (int it = 0; it < 16; ++it) {
        int idx = it * 256 + tid;
        int rr = idx >> 5;
        int c4 = (idx & 31) << 2;
        *(float4*)&C[(size_t)(bi * 128 + rr) * NN + bj * 128 + c4] = z;
    }
}

// ---------------- main GEMM: 128x128 tile, BK=32, split-K (max 32 steps/unit) ----------------
// grid = 1000 units: unit -> (d, tile-on-diagonal, k-chunk). chunks/tile m = ceil((d+1)/8).
__global__ __launch_bounds__(256, 2) void gemm_tril_sk(const unsigned short* __restrict__ Abf,
                                                       const unsigned short* __restrict__ Btb,
                                                       float* __restrict__ C) {
    const int tid = threadIdx.x;

    // decode unit id -> (bi, bj, chunk c, chunks-per-tile m)
    int u = blockIdx.x, d, m = 1;
    for (d = 0; d < 32; ++d) {
        m = (d + 8) >> 3;                       // ceil((d+1)/8)
        int cnt = (32 - d) * m;
        if (u < cnt) break;
        u -= cnt;
    }
    const int blk = u / m;
    const int c   = u - blk * m;
    const int bj = blk, bi = blk + d;

    __shared__ __attribute__((aligned(16))) unsigned short As[128 * 32];
    __shared__ __attribute__((aligned(16))) unsigned short Bs[128 * 32];

    const int lane = tid & 63;
    const int w    = tid >> 6;
    const int wm   = w >> 1, wn = w & 1;
    const int l15  = lane & 15, quad = lane >> 4;

    f32x4 acc[4][4];
    const f32x4 zero4 = {0.f, 0.f, 0.f, 0.f};
    #pragma unroll
    for (int i = 0; i < 4; ++i)
        #pragma unroll
        for (int j = 0; j < 4; ++j) acc[i][j] = zero4;

    const int kbB = (bj << 2) + c * 32;
    const int kbE = min(kbB + 32, (bi << 2) + 4);   // exclusive

    for (int kb = kbB; kb < kbE; ++kb) {
        const int koff = kb << 5;
        #pragma unroll
        for (int u2 = 0; u2 < 2; ++u2) {
            int ci   = u2 * 256 + tid;          // 16B chunk id, 512 per tile
            int rowA = ci >> 2;
            int q    = ci & 3;
            load_lds16(Abf + (size_t)(bi * 128 + rowA) * NN + koff + q * 8, &As[ci * 8]);
            load_lds16(Btb + (size_t)(bj * 128 + rowA) * NN + koff + q * 8, &Bs[ci * 8]);
        }
        __syncthreads();

        short8 a[4], b[4];
        #pragma unroll
        for (int mt = 0; mt < 4; ++mt)
            a[mt] = *(const short8*)&As[(wm * 64 + mt * 16 + l15) * 32 + quad * 8];
        #pragma unroll
        for (int nt = 0; nt < 4; ++nt)
            b[nt] = *(const short8*)&Bs[(wn * 64 + nt * 16 + l15) * 32 + quad * 8];
        #pragma unroll
        for (int mt = 0; mt < 4; ++mt)
            #pragma unroll
            for (int nt = 0; nt < 4; ++nt)
                acc[mt][nt] = __builtin_amdgcn_mfma_f32_16x16x32_bf16(a[mt], b[nt], acc[mt][nt], 0, 0, 0);
        __syncthreads();
    }

    // epilogue: C/D layout col=lane&15, row=quad*4+reg (m89-verified)
    if (m == 1) {
        // sole owner of this tile: direct store (covers all 128x128; mask only if diagonal tile)
        #pragma unroll
        for (int mt = 0; mt < 4; ++mt) {
            #pragma unroll
            for (int nt = 0; nt < 4; ++nt) {
                const int gj  = bj * 128 + wn * 64 + nt * 16 + l15;
                const int gi0 = bi * 128 + wm * 64 + mt * 16 + quad * 4;
                #pragma unroll
                for (int rr = 0; rr < 4; ++rr) {
                    int gi = gi0 + rr;
                    float v = acc[mt][nt][rr];
                    C[(size_t)gi * NN + gj] = (d > 0 || gi >= gj) ? v : 0.f;
                }
            }
        }
    } else {
        // partial contribution: tile was pre-zeroed; d>=8 so strictly lower, no mask
        #pragma unroll
        for (int mt = 0; mt < 4; ++mt) {
            #pragma unroll
            for (int nt = 0; nt < 4; ++nt) {
                const int gj  = bj * 128 + wn * 64 + nt * 16 + l15;
                const int gi0 = bi * 128 + wm * 64 + mt * 16 + quad * 4;
                #pragma unroll
                for (int rr = 0; rr < 4; ++rr) {
                    int gi = gi0 + rr;
                    atomicAdd(&C[(size_t)gi * NN + gj], acc[mt][nt][rr]);
                }
            }
        }
    }
}

// ---------------- fallback (ws too small): fp32 LDS-tiled, correct-but-slow ----------------
__global__ void gemm_fallback(const float* __restrict__ A, const float* __restrict__ B,
                              float* __restrict__ C) {
    const int bi = blockIdx.y, bj = blockIdx.x;
    const int ty = threadIdx.y, tx = threadIdx.x;
    const int gi = bi * 32 + ty, gj = bj * 32 + tx;
    if (bi < bj) { C[(size_t)gi * NN + gj] = 0.f; return; }
    __shared__ float As[32][33], Bs[32][33];
    float s = 0.f;
    for (int kt = bj; kt <= bi; ++kt) {
        const int k = kt * 32;
        float av = A[(size_t)gi * NN + k + tx];
        As[ty][tx] = (k + tx <= gi) ? av : 0.f;
        float bv = B[(size_t)(k + ty) * NN + gj];
        Bs[ty][tx] = (k + ty >= gj) ? bv : 0.f;
        __syncthreads();
        #pragma unroll
        for (int kk = 0; kk < 32; ++kk) s += As[ty][kk] * Bs[kk][tx];
        __syncthreads();
    }
    C[(size_t)gi * NN + gj] = (gi >= gj) ? s : 0.f;
}

extern "C" void kernel_launch(void* const* d_in, const int* in_sizes, int n_in,
                              void* d_out, int out_size, void* d_ws, size_t ws_size,
                              hipStream_t stream) {
    const float* A = (const float*)d_in[0];
    const float* B = (const float*)d_in[1];
    float* C = (float*)d_out;

    const size_t need = (size_t)2 * NN * NN * sizeof(unsigned short);  // 64 MB
    if (ws_size >= need) {
        unsigned short* Abf = (unsigned short*)d_ws;
        unsigned short* Btb = Abf + (size_t)NN * NN;
        convA<<<dim3(16384), dim3(256), 0, stream>>>(A, Abf);
        convB<<<dim3(64, 64), dim3(256), 0, stream>>>(B, Btb);
        prep_zero<<<dim3(796), dim3(256), 0, stream>>>(C);
        gemm_tril_sk<<<dim3(1000), dim3(256), 0, stream>>>(Abf, Btb, C);
    } else {
        gemm_fallback<<<dim3(128, 128), dim3(32, 32), 0, stream>>>(A, B, C);
    }
}